// Round 8
// baseline (673.524 us; speedup 1.0000x reference)
//
#include <hip/hip_runtime.h>
#include <hip/hip_cooperative_groups.h>

namespace cg = cooperative_groups;

typedef unsigned short u16;
typedef unsigned int u32;
typedef short short8 __attribute__((ext_vector_type(8)));
typedef short short4v __attribute__((ext_vector_type(4)));
typedef float floatx4 __attribute__((ext_vector_type(4)));

#define NE 800000
#define NNODES 50000
#define NBLK 196  // ceil(50000/256)

#define LDS_FENCE() __asm__ volatile("s_waitcnt lgkmcnt(0)" ::: "memory")

__device__ __forceinline__ u16 f2bf(float f) {
    union { float f; unsigned int i; } v; v.f = f;
    return (u16)((v.i + 0x7fffu + ((v.i >> 16) & 1u)) >> 16);
}
__device__ __forceinline__ float bf2f(u16 u) {
    union { unsigned int i; float f; } v; v.i = ((unsigned int)u) << 16; return v.f;
}
__device__ __forceinline__ short8 ld8_bf(const float* __restrict__ p) {
    const float4 a = *(const float4*)p;
    const float4 b = *(const float4*)(p + 4);
    short8 o;
    o[0] = (short)f2bf(a.x); o[1] = (short)f2bf(a.y);
    o[2] = (short)f2bf(a.z); o[3] = (short)f2bf(a.w);
    o[4] = (short)f2bf(b.x); o[5] = (short)f2bf(b.y);
    o[6] = (short)f2bf(b.z); o[7] = (short)f2bf(b.w);
    return o;
}

#define MFMA16(a, b, c) __builtin_amdgcn_mfma_f32_16x16x32_bf16(a, b, c, 0, 0, 0)

// LDS: phases overlay. edge=31.0 KB, node=17.4 KB, scan tiny.
union SMem {
    struct {
        u16 A1[4][16 * 104];   // 13312 B
        u16 Hs[4][16 * 72];    //  9216 B
        u16 W2f[2][4][64 * 8]; //  8192 B
        int Ds[4][16];         //   256 B
    } e;
    struct {
        u16 Cs[4][16 * 136];   // 17408 B
    } n;
    struct {
        int ws[4];
    } s;
};

__global__ __launch_bounds__(256, 4) void fused_kernel(
    const float* __restrict__ x, const int* __restrict__ ei,
    const float* __restrict__ ef, const float* __restrict__ w1,
    const float* __restrict__ b1, const float* __restrict__ w2,
    const float* __restrict__ b2, const float* __restrict__ w3,
    const float* __restrict__ b3, const float* __restrict__ g,
    const float* __restrict__ bb, int* __restrict__ ws_base,
    float* __restrict__ out)
{
    cg::grid_group grid = cg::this_grid();
    __shared__ SMem sm;

    // ws layout (u32 units): agg[3.2M] | hist[50k] | cursor[50k] | bsum[256]
    //                        | bsumx[256] | xbf[1.6M] | sde[1.6M]
    float* agg   = (float*)ws_base;
    int* hist    = ws_base + 3200000;
    int* cursor  = hist + NNODES;
    int* bsum    = cursor + NNODES;
    int* bsumx   = bsum + 256;
    u16* xbf     = (u16*)(bsumx + 256);
    uint2* sde   = (uint2*)(ws_base + 4900512);

    const int tid  = blockIdx.x * 256 + threadIdx.x;
    const int nthr = gridDim.x * 256;
    const int wid  = threadIdx.x >> 6;
    const int lane = threadIdx.x & 63;
    const int q    = lane >> 4;
    const int c    = lane & 15;

    // ---------------- phase 0: zero agg + hist + cursor (contiguous 3.3M words)
    {
        float4* zb = (float4*)ws_base;
        const float4 z4 = {0.f, 0.f, 0.f, 0.f};
        for (int i = tid; i < 825000; i += nthr) zb[i] = z4;
    }
    grid.sync();

    // ---------------- phase 1: dst histogram + x -> bf16
    for (int i = tid; i < NE; i += nthr) atomicAdd(&hist[ei[NE + i]], 1);
    for (int i = tid; i < NNODES * 8; i += nthr)
        *(short8*)&xbf[(size_t)i * 8] = ld8_bf(x + (size_t)i * 8);
    grid.sync();

    // ---------------- phase 2: per-chunk exclusive scan (first NBLK blocks)
    if (blockIdx.x < NBLK) {
        const int i = blockIdx.x * 256 + threadIdx.x;
        const int v = (i < NNODES) ? hist[i] : 0;
        int inc = v;
        #pragma unroll
        for (int o = 1; o < 64; o <<= 1) {
            const int tt = __shfl_up(inc, o);
            if (lane >= o) inc += tt;
        }
        if (lane == 63) sm.s.ws[wid] = inc;
        __syncthreads();
        int add = 0;
        for (int j = 0; j < wid; ++j) add += sm.s.ws[j];
        const int excl = inc - v + add;
        if (i < NNODES) cursor[i] = excl;
        if (threadIdx.x == 255) bsum[blockIdx.x] = excl + v;
    }
    grid.sync();

    // ---------------- phase 3: scan chunk totals (block 0)
    if (blockIdx.x == 0) {
        const int v = (threadIdx.x < NBLK) ? bsum[threadIdx.x] : 0;
        int inc = v;
        #pragma unroll
        for (int o = 1; o < 64; o <<= 1) {
            const int tt = __shfl_up(inc, o);
            if (lane >= o) inc += tt;
        }
        if (lane == 63) sm.s.ws[wid] = inc;
        __syncthreads();
        int add = 0;
        for (int j = 0; j < wid; ++j) add += sm.s.ws[j];
        bsumx[threadIdx.x] = inc - v + add;
    }
    grid.sync();

    // ---------------- phase 4: scatter packed records (dst-sorted)
    for (int e = tid; e < NE; e += nthr) {
        const int dst = ei[NE + e];
        const int p = atomicAdd(&cursor[dst], 1) + bsumx[dst >> 8];
        uint2 v;
        v.x = (u32)e;
        v.y = ((u32)ei[e] << 16) | (u32)dst;
        sde[p] = v;
    }
    grid.sync();

    // ---------------- phase 5: edge MLP + segmented aggregate
    {
        constexpr int S1 = 104;
        constexpr int S2 = 72;
        const int r4 = lane >> 2;
        const int p4 = lane & 3;

        // W1 B-frags in registers. B[k][n]: n=16*nn+c, k=32*kk+q*8+j
        short8 w1f[3][4];
        #pragma unroll
        for (int kk = 0; kk < 3; ++kk)
            #pragma unroll
            for (int nn = 0; nn < 4; ++nn)
                #pragma unroll
                for (int j = 0; j < 8; ++j) {
                    const int k = kk * 32 + q * 8 + j;
                    w1f[kk][nn][j] = (k < 80) ? (short)f2bf(w1[k * 64 + nn * 16 + c]) : (short)0;
                }
        // W2 B-frags into LDS once
        if (wid == 0) {
            #pragma unroll
            for (int kk = 0; kk < 2; ++kk)
                #pragma unroll
                for (int nn = 0; nn < 4; ++nn) {
                    short8 f;
                    #pragma unroll
                    for (int j = 0; j < 8; ++j) {
                        const int k = kk * 32 + q * 8 + j;
                        f[j] = (short)f2bf(w2[k * 64 + nn * 16 + c]);
                    }
                    *(short8*)&sm.e.W2f[kk][nn][lane * 8] = f;
                }
        }
        float b1v[4], b2v[4];
        #pragma unroll
        for (int nn = 0; nn < 4; ++nn) {
            b1v[nn] = b1[nn * 16 + c];
            b2v[nn] = b2[nn * 16 + c];
        }
        __syncthreads();
        // zero pad region (cols 80..96) once
        if (q == 1) {
            const short8 z8 = {0, 0, 0, 0, 0, 0, 0, 0};
            *(short8*)&sm.e.A1[wid][c * S1 + 80] = z8;
            *(short8*)&sm.e.A1[wid][c * S1 + 88] = z8;
        }

        const floatx4 zero = {0.f, 0.f, 0.f, 0.f};
        const int ntile = NE / 16;  // 50000
        const int stride = gridDim.x * 4;
        int t = blockIdx.x * 4 + wid;

        // prologue: idx for t and t+stride, data for t
        uint2 sdB; u32 eB;
        short8 xa, xb; float4 ev;
        int dcur;
        {
            const uint2 sdA = sde[t * 16 + c];
            const u32  eA  = sde[t * 16 + r4].x;
            dcur = (int)(sdA.y & 0xffffu);
            const int sA = (int)(sdA.y >> 16);
            int tb = t + stride; if (tb >= ntile) tb = ntile - 1;
            sdB = sde[tb * 16 + c];
            eB  = sde[tb * 16 + r4].x;
            const u16* xp = xbf + (size_t)sA * 64 + q * 16;
            xa = *(const short8*)xp;
            xb = *(const short8*)(xp + 8);
            ev = *(const float4*)(ef + (size_t)eA * 16 + p4 * 4);
        }

        for (; t < ntile; t += stride) {
            u16* arow = &sm.e.A1[wid][c * S1 + q * 16];
            *(short8*)arow       = xa;
            *(short8*)(arow + 8) = xb;
            {
                short4v e4;
                e4[0] = (short)f2bf(ev.x); e4[1] = (short)f2bf(ev.y);
                e4[2] = (short)f2bf(ev.z); e4[3] = (short)f2bf(ev.w);
                *(short4v*)&sm.e.A1[wid][r4 * S1 + 64 + p4 * 4] = e4;
            }
            if (q == 0) sm.e.Ds[wid][c] = dcur;
            LDS_FENCE();

            short8 a1k[3];
            #pragma unroll
            for (int kk = 0; kk < 3; ++kk)
                a1k[kk] = *(const short8*)&sm.e.A1[wid][c * S1 + kk * 32 + q * 8];

            // prefetch data for t+stride
            const int dnext = (int)(sdB.y & 0xffffu);
            {
                const int sN = (int)(sdB.y >> 16);
                const u16* xp = xbf + (size_t)sN * 64 + q * 16;
                xa = *(const short8*)xp;
                xb = *(const short8*)(xp + 8);
                ev = *(const float4*)(ef + (size_t)eB * 16 + p4 * 4);
            }
            {
                int tb = t + 2 * stride; if (tb >= ntile) tb = ntile - 1;
                sdB = sde[tb * 16 + c];
                eB  = sde[tb * 16 + r4].x;
            }

            // GEMM1 + bias + relu -> Hs
            #pragma unroll
            for (int nn = 0; nn < 4; ++nn) {
                floatx4 acc = MFMA16(a1k[0], w1f[0][nn], zero);
                acc = MFMA16(a1k[1], w1f[1][nn], acc);
                acc = MFMA16(a1k[2], w1f[2][nn], acc);
                #pragma unroll
                for (int r = 0; r < 4; ++r) {
                    const float h = fmaxf(acc[r] + b1v[nn], 0.f);
                    sm.e.Hs[wid][(q * 4 + r) * S2 + nn * 16 + c] = f2bf(h);
                }
            }
            LDS_FENCE();

            short8 a2k[2];
            #pragma unroll
            for (int kk = 0; kk < 2; ++kk)
                a2k[kk] = *(const short8*)&sm.e.Hs[wid][c * S2 + kk * 32 + q * 8];

            // GEMM2 -> msg (bf16) overlaid into Hs
            #pragma unroll
            for (int nn = 0; nn < 4; ++nn) {
                const short8 wf0 = *(const short8*)&sm.e.W2f[0][nn][lane * 8];
                const short8 wf1 = *(const short8*)&sm.e.W2f[1][nn][lane * 8];
                floatx4 mg = MFMA16(a2k[0], wf0, zero);
                mg = MFMA16(a2k[1], wf1, mg);
                #pragma unroll
                for (int r = 0; r < 4; ++r)
                    sm.e.Hs[wid][(q * 4 + r) * S2 + nn * 16 + c] = f2bf(mg[r] + b2v[nn]);
            }
            LDS_FENCE();

            // segmented reduction over sorted dst (lane = column)
            int dc = sm.e.Ds[wid][0];
            float acc = bf2f(sm.e.Hs[wid][lane]);
            #pragma unroll
            for (int row = 1; row < 16; ++row) {
                const int d = sm.e.Ds[wid][row];
                const float v = bf2f(sm.e.Hs[wid][row * S2 + lane]);
                if (d == dc) {
                    acc += v;
                } else {
                    atomicAdd(&agg[(size_t)dc * 64 + lane], acc);
                    dc = d;
                    acc = v;
                }
            }
            atomicAdd(&agg[(size_t)dc * 64 + lane], acc);

            dcur = dnext;
        }
    }
    grid.sync();

    // ---------------- phase 6: node update + LayerNorm
    {
        constexpr int S3 = 136;

        short8 w3f[4][4];
        #pragma unroll
        for (int kk = 0; kk < 4; ++kk)
            #pragma unroll
            for (int nn = 0; nn < 4; ++nn)
                #pragma unroll
                for (int j = 0; j < 8; ++j) {
                    const int k = kk * 32 + q * 8 + j;
                    w3f[kk][nn][j] = (short)f2bf(w3[k * 64 + nn * 16 + c]);
                }
        float b3v[4], gv[4], bv[4];
        #pragma unroll
        for (int nn = 0; nn < 4; ++nn) {
            b3v[nn] = b3[nn * 16 + c];
            gv[nn]  = g[nn * 16 + c];
            bv[nn]  = bb[nn * 16 + c];
        }

        const floatx4 zero = {0.f, 0.f, 0.f, 0.f};
        const int ntile = NNODES / 16;  // 3125

        for (int t = blockIdx.x * 4 + wid; t < ntile; t += gridDim.x * 4) {
            const int n0 = t * 16;
            const int node = n0 + c;
            u16* crow = &sm.n.Cs[wid][c * S3];

            if (q < 2) {
                const u16* xp = xbf + (size_t)node * 64 + q * 32;
                *(short8*)&crow[q * 32]      = *(const short8*)xp;
                *(short8*)&crow[q * 32 + 8]  = *(const short8*)(xp + 8);
                *(short8*)&crow[q * 32 + 16] = *(const short8*)(xp + 16);
                *(short8*)&crow[q * 32 + 24] = *(const short8*)(xp + 24);
            } else {
                const int p = q - 2;
                const float inv = 1.0f / ((float)hist[node] + 1e-8f);
                const float* ap = agg + (size_t)node * 64 + p * 32;
                #pragma unroll
                for (int gi = 0; gi < 4; ++gi) {
                    const float4 v0 = *(const float4*)(ap + gi * 8);
                    const float4 v1 = *(const float4*)(ap + gi * 8 + 4);
                    short8 o;
                    o[0] = (short)f2bf(v0.x * inv);
                    o[1] = (short)f2bf(v0.y * inv);
                    o[2] = (short)f2bf(v0.z * inv);
                    o[3] = (short)f2bf(v0.w * inv);
                    o[4] = (short)f2bf(v1.x * inv);
                    o[5] = (short)f2bf(v1.y * inv);
                    o[6] = (short)f2bf(v1.z * inv);
                    o[7] = (short)f2bf(v1.w * inv);
                    *(short8*)&crow[64 + p * 32 + gi * 8] = o;
                }
            }
            LDS_FENCE();

            short8 af[4];
            #pragma unroll
            for (int kk = 0; kk < 4; ++kk)
                af[kk] = *(const short8*)&sm.n.Cs[wid][c * S3 + kk * 32 + q * 8];

            float y[4][4];
            float s[4]  = {0.f, 0.f, 0.f, 0.f};
            float ss[4] = {0.f, 0.f, 0.f, 0.f};
            #pragma unroll
            for (int nn = 0; nn < 4; ++nn) {
                floatx4 acc = MFMA16(af[0], w3f[0][nn], zero);
                acc = MFMA16(af[1], w3f[1][nn], acc);
                acc = MFMA16(af[2], w3f[2][nn], acc);
                acc = MFMA16(af[3], w3f[3][nn], acc);
                #pragma unroll
                for (int r = 0; r < 4; ++r) {
                    const float upd = fmaxf(acc[r] + b3v[nn], 0.f);
                    const float xv = bf2f(sm.n.Cs[wid][(q * 4 + r) * S3 + nn * 16 + c]);
                    const float yy = upd + xv;
                    y[r][nn] = yy;
                    s[r] += yy;
                    ss[r] += yy * yy;
                }
            }

            #pragma unroll
            for (int r = 0; r < 4; ++r) {
                float sr = s[r], sq = ss[r];
                #pragma unroll
                for (int off = 1; off < 16; off <<= 1) {
                    sr += __shfl_xor(sr, off);
                    sq += __shfl_xor(sq, off);
                }
                const float mu  = sr * (1.0f / 64.0f);
                const float var = sq * (1.0f / 64.0f) - mu * mu;
                const float rs  = rsqrtf(var + 1e-5f);
                float* op = out + (size_t)(n0 + q * 4 + r) * 64 + c;
                #pragma unroll
                for (int nn = 0; nn < 4; ++nn)
                    op[nn * 16] = (y[r][nn] - mu) * rs * gv[nn] + bv[nn];
            }
        }
    }
}

extern "C" void kernel_launch(void* const* d_in, const int* in_sizes, int n_in,
                              void* d_out, int out_size, void* d_ws, size_t ws_size,
                              hipStream_t stream) {
    const float* x   = (const float*)d_in[0];
    const int*   ei  = (const int*)d_in[1];
    const float* ef  = (const float*)d_in[2];
    const float* w1  = (const float*)d_in[3];
    const float* b1  = (const float*)d_in[4];
    const float* w2  = (const float*)d_in[5];
    const float* b2  = (const float*)d_in[6];
    const float* w3  = (const float*)d_in[7];
    const float* b3  = (const float*)d_in[8];
    const float* g   = (const float*)d_in[9];
    const float* bb  = (const float*)d_in[10];
    int* ws  = (int*)d_ws;
    float* out = (float*)d_out;

    int maxb = 4;
    hipOccupancyMaxActiveBlocksPerMultiprocessor(&maxb, fused_kernel, 256, 0);
    if (maxb < 1) maxb = 1;
    int grid = maxb * 256;           // 256 CUs on MI355X
    if (grid > 1280) grid = 1280;
    if (grid < 256) grid = 256;      // scan phase needs >= 196 blocks

    void* args[] = { (void*)&x, (void*)&ei, (void*)&ef, (void*)&w1, (void*)&b1,
                     (void*)&w2, (void*)&b2, (void*)&w3, (void*)&b3, (void*)&g,
                     (void*)&bb, (void*)&ws, (void*)&out };
    hipLaunchCooperativeKernel((void*)fused_kernel, dim3(grid), dim3(256),
                               args, 0, stream);
}

// Round 9
// 515.725 us; speedup vs baseline: 1.3060x; 1.3060x over previous
//
#include <hip/hip_runtime.h>
#include <hip/hip_cooperative_groups.h>

namespace cg = cooperative_groups;

typedef unsigned short u16;
typedef unsigned int u32;
typedef short short8 __attribute__((ext_vector_type(8)));
typedef short short4v __attribute__((ext_vector_type(4)));
typedef float floatx4 __attribute__((ext_vector_type(4)));

#define NE 800000
#define NNODES 50000
#define NBLK 196  // ceil(50000/256)

#define LDS_FENCE() __asm__ volatile("s_waitcnt lgkmcnt(0)" ::: "memory")

__device__ __forceinline__ u16 f2bf(float f) {
    union { float f; unsigned int i; } v; v.f = f;
    return (u16)((v.i + 0x7fffu + ((v.i >> 16) & 1u)) >> 16);
}
__device__ __forceinline__ float bf2f(u16 u) {
    union { unsigned int i; float f; } v; v.i = ((unsigned int)u) << 16; return v.f;
}
__device__ __forceinline__ short8 ld8_bf(const float* __restrict__ p) {
    const float4 a = *(const float4*)p;
    const float4 b = *(const float4*)(p + 4);
    short8 o;
    o[0] = (short)f2bf(a.x); o[1] = (short)f2bf(a.y);
    o[2] = (short)f2bf(a.z); o[3] = (short)f2bf(a.w);
    o[4] = (short)f2bf(b.x); o[5] = (short)f2bf(b.y);
    o[6] = (short)f2bf(b.z); o[7] = (short)f2bf(b.w);
    return o;
}

#define MFMA16(a, b, c) __builtin_amdgcn_mfma_f32_16x16x32_bf16(a, b, c, 0, 0, 0)

// LDS: phases overlay. edge=31.0 KB, node=17.4 KB, scan tiny.
union SMem {
    struct {
        u16 A1[4][16 * 104];   // 13312 B
        u16 Hs[4][16 * 72];    //  9216 B
        u16 W2f[2][4][64 * 8]; //  8192 B
        int Ds[4][16];         //   256 B
    } e;
    struct {
        u16 Cs[4][16 * 136];   // 17408 B
    } n;
    struct {
        int ws[4];
    } s;
};

// NOTE: plain __launch_bounds__(256). (256,4) forced VGPR=64 -> K-loop spills
// (WRITE_SIZE 24->171 MB, 673 us). LDS (31.25 KB) caps occupancy at 5 blk/CU.
__global__ __launch_bounds__(256) void fused_kernel(
    const float* __restrict__ x, const int* __restrict__ ei,
    const float* __restrict__ ef, const float* __restrict__ w1,
    const float* __restrict__ b1, const float* __restrict__ w2,
    const float* __restrict__ b2, const float* __restrict__ w3,
    const float* __restrict__ b3, const float* __restrict__ g,
    const float* __restrict__ bb, int* __restrict__ ws_base,
    float* __restrict__ out)
{
    cg::grid_group grid = cg::this_grid();
    __shared__ SMem sm;

    // ws layout (u32 units): agg[3.2M] | hist[50k] | cursor[50k] | bsum[256]
    //                        | bsumx[256] | xbf[1.6M] | sde[1.6M]
    float* agg   = (float*)ws_base;
    int* hist    = ws_base + 3200000;
    int* cursor  = hist + NNODES;
    int* bsum    = cursor + NNODES;
    int* bsumx   = bsum + 256;
    u16* xbf     = (u16*)(bsumx + 256);
    uint2* sde   = (uint2*)(ws_base + 4900512);

    const int tid  = blockIdx.x * 256 + threadIdx.x;
    const int nthr = gridDim.x * 256;
    const int wid  = threadIdx.x >> 6;
    const int lane = threadIdx.x & 63;
    const int q    = lane >> 4;
    const int c    = lane & 15;

    // ---------------- phase 0: zero agg + hist + cursor (contiguous)
    {
        float4* zb = (float4*)ws_base;
        const float4 z4 = {0.f, 0.f, 0.f, 0.f};
        for (int i = tid; i < 825000; i += nthr) zb[i] = z4;
    }
    grid.sync();

    // ---------------- phase 1: dst histogram + x -> bf16
    for (int i = tid; i < NE; i += nthr) atomicAdd(&hist[ei[NE + i]], 1);
    for (int i = tid; i < NNODES * 8; i += nthr)
        *(short8*)&xbf[(size_t)i * 8] = ld8_bf(x + (size_t)i * 8);
    grid.sync();

    // ---------------- phase 2: per-chunk exclusive scan (first NBLK blocks)
    if (blockIdx.x < NBLK) {
        const int i = blockIdx.x * 256 + threadIdx.x;
        const int v = (i < NNODES) ? hist[i] : 0;
        int inc = v;
        #pragma unroll
        for (int o = 1; o < 64; o <<= 1) {
            const int tt = __shfl_up(inc, o);
            if (lane >= o) inc += tt;
        }
        if (lane == 63) sm.s.ws[wid] = inc;
        __syncthreads();
        int add = 0;
        for (int j = 0; j < wid; ++j) add += sm.s.ws[j];
        const int excl = inc - v + add;
        if (i < NNODES) cursor[i] = excl;
        if (threadIdx.x == 255) bsum[blockIdx.x] = excl + v;
    }
    grid.sync();

    // ---------------- phase 3: scan chunk totals (block 0)
    if (blockIdx.x == 0) {
        const int v = (threadIdx.x < NBLK) ? bsum[threadIdx.x] : 0;
        int inc = v;
        #pragma unroll
        for (int o = 1; o < 64; o <<= 1) {
            const int tt = __shfl_up(inc, o);
            if (lane >= o) inc += tt;
        }
        if (lane == 63) sm.s.ws[wid] = inc;
        __syncthreads();
        int add = 0;
        for (int j = 0; j < wid; ++j) add += sm.s.ws[j];
        bsumx[threadIdx.x] = inc - v + add;
    }
    grid.sync();

    // ---------------- phase 4: scatter packed records (dst-sorted)
    for (int e = tid; e < NE; e += nthr) {
        const int dst = ei[NE + e];
        const int p = atomicAdd(&cursor[dst], 1) + bsumx[dst >> 8];
        uint2 v;
        v.x = (u32)e;
        v.y = ((u32)ei[e] << 16) | (u32)dst;
        sde[p] = v;
    }
    grid.sync();

    // ---------------- phase 5: edge MLP + segmented aggregate
    {
        constexpr int S1 = 104;
        constexpr int S2 = 72;
        const int r4 = lane >> 2;
        const int p4 = lane & 3;

        // W1 B-frags in registers. B[k][n]: n=16*nn+c, k=32*kk+q*8+j
        short8 w1f[3][4];
        #pragma unroll
        for (int kk = 0; kk < 3; ++kk)
            #pragma unroll
            for (int nn = 0; nn < 4; ++nn)
                #pragma unroll
                for (int j = 0; j < 8; ++j) {
                    const int k = kk * 32 + q * 8 + j;
                    w1f[kk][nn][j] = (k < 80) ? (short)f2bf(w1[k * 64 + nn * 16 + c]) : (short)0;
                }
        // W2 B-frags into LDS once
        if (wid == 0) {
            #pragma unroll
            for (int kk = 0; kk < 2; ++kk)
                #pragma unroll
                for (int nn = 0; nn < 4; ++nn) {
                    short8 f;
                    #pragma unroll
                    for (int j = 0; j < 8; ++j) {
                        const int k = kk * 32 + q * 8 + j;
                        f[j] = (short)f2bf(w2[k * 64 + nn * 16 + c]);
                    }
                    *(short8*)&sm.e.W2f[kk][nn][lane * 8] = f;
                }
        }
        float b1v[4], b2v[4];
        #pragma unroll
        for (int nn = 0; nn < 4; ++nn) {
            b1v[nn] = b1[nn * 16 + c];
            b2v[nn] = b2[nn * 16 + c];
        }
        __syncthreads();
        // zero pad region (cols 80..96) once
        if (q == 1) {
            const short8 z8 = {0, 0, 0, 0, 0, 0, 0, 0};
            *(short8*)&sm.e.A1[wid][c * S1 + 80] = z8;
            *(short8*)&sm.e.A1[wid][c * S1 + 88] = z8;
        }

        const floatx4 zero = {0.f, 0.f, 0.f, 0.f};
        const int ntile = NE / 16;  // 50000
        const int stride = gridDim.x * 4;
        int t = blockIdx.x * 4 + wid;

        // prologue: idx for t and t+stride, data for t
        uint2 sdB; u32 eB;
        short8 xa, xb; float4 ev;
        int dcur;
        {
            const uint2 sdA = sde[t * 16 + c];
            const u32  eA  = sde[t * 16 + r4].x;
            dcur = (int)(sdA.y & 0xffffu);
            const int sA = (int)(sdA.y >> 16);
            int tb = t + stride; if (tb >= ntile) tb = ntile - 1;
            sdB = sde[tb * 16 + c];
            eB  = sde[tb * 16 + r4].x;
            const u16* xp = xbf + (size_t)sA * 64 + q * 16;
            xa = *(const short8*)xp;
            xb = *(const short8*)(xp + 8);
            ev = *(const float4*)(ef + (size_t)eA * 16 + p4 * 4);
        }

        for (; t < ntile; t += stride) {
            u16* arow = &sm.e.A1[wid][c * S1 + q * 16];
            *(short8*)arow       = xa;
            *(short8*)(arow + 8) = xb;
            {
                short4v e4;
                e4[0] = (short)f2bf(ev.x); e4[1] = (short)f2bf(ev.y);
                e4[2] = (short)f2bf(ev.z); e4[3] = (short)f2bf(ev.w);
                *(short4v*)&sm.e.A1[wid][r4 * S1 + 64 + p4 * 4] = e4;
            }
            if (q == 0) sm.e.Ds[wid][c] = dcur;
            LDS_FENCE();

            short8 a1k[3];
            #pragma unroll
            for (int kk = 0; kk < 3; ++kk)
                a1k[kk] = *(const short8*)&sm.e.A1[wid][c * S1 + kk * 32 + q * 8];

            // prefetch data for t+stride
            const int dnext = (int)(sdB.y & 0xffffu);
            {
                const int sN = (int)(sdB.y >> 16);
                const u16* xp = xbf + (size_t)sN * 64 + q * 16;
                xa = *(const short8*)xp;
                xb = *(const short8*)(xp + 8);
                ev = *(const float4*)(ef + (size_t)eB * 16 + p4 * 4);
            }
            {
                int tb = t + 2 * stride; if (tb >= ntile) tb = ntile - 1;
                sdB = sde[tb * 16 + c];
                eB  = sde[tb * 16 + r4].x;
            }

            // GEMM1 + bias + relu -> Hs
            #pragma unroll
            for (int nn = 0; nn < 4; ++nn) {
                floatx4 acc = MFMA16(a1k[0], w1f[0][nn], zero);
                acc = MFMA16(a1k[1], w1f[1][nn], acc);
                acc = MFMA16(a1k[2], w1f[2][nn], acc);
                #pragma unroll
                for (int r = 0; r < 4; ++r) {
                    const float h = fmaxf(acc[r] + b1v[nn], 0.f);
                    sm.e.Hs[wid][(q * 4 + r) * S2 + nn * 16 + c] = f2bf(h);
                }
            }
            LDS_FENCE();

            short8 a2k[2];
            #pragma unroll
            for (int kk = 0; kk < 2; ++kk)
                a2k[kk] = *(const short8*)&sm.e.Hs[wid][c * S2 + kk * 32 + q * 8];

            // GEMM2 -> msg (bf16) overlaid into Hs
            #pragma unroll
            for (int nn = 0; nn < 4; ++nn) {
                const short8 wf0 = *(const short8*)&sm.e.W2f[0][nn][lane * 8];
                const short8 wf1 = *(const short8*)&sm.e.W2f[1][nn][lane * 8];
                floatx4 mg = MFMA16(a2k[0], wf0, zero);
                mg = MFMA16(a2k[1], wf1, mg);
                #pragma unroll
                for (int r = 0; r < 4; ++r)
                    sm.e.Hs[wid][(q * 4 + r) * S2 + nn * 16 + c] = f2bf(mg[r] + b2v[nn]);
            }
            LDS_FENCE();

            // segmented reduction over sorted dst (lane = column)
            int dc = sm.e.Ds[wid][0];
            float acc = bf2f(sm.e.Hs[wid][lane]);
            #pragma unroll
            for (int row = 1; row < 16; ++row) {
                const int d = sm.e.Ds[wid][row];
                const float v = bf2f(sm.e.Hs[wid][row * S2 + lane]);
                if (d == dc) {
                    acc += v;
                } else {
                    atomicAdd(&agg[(size_t)dc * 64 + lane], acc);
                    dc = d;
                    acc = v;
                }
            }
            atomicAdd(&agg[(size_t)dc * 64 + lane], acc);

            dcur = dnext;
        }
    }
    grid.sync();

    // ---------------- phase 6: node update + LayerNorm
    {
        constexpr int S3 = 136;

        short8 w3f[4][4];
        #pragma unroll
        for (int kk = 0; kk < 4; ++kk)
            #pragma unroll
            for (int nn = 0; nn < 4; ++nn)
                #pragma unroll
                for (int j = 0; j < 8; ++j) {
                    const int k = kk * 32 + q * 8 + j;
                    w3f[kk][nn][j] = (short)f2bf(w3[k * 64 + nn * 16 + c]);
                }
        float b3v[4], gv[4], bv[4];
        #pragma unroll
        for (int nn = 0; nn < 4; ++nn) {
            b3v[nn] = b3[nn * 16 + c];
            gv[nn]  = g[nn * 16 + c];
            bv[nn]  = bb[nn * 16 + c];
        }

        const floatx4 zero = {0.f, 0.f, 0.f, 0.f};
        const int ntile = NNODES / 16;  // 3125

        for (int t = blockIdx.x * 4 + wid; t < ntile; t += gridDim.x * 4) {
            const int n0 = t * 16;
            const int node = n0 + c;
            u16* crow = &sm.n.Cs[wid][c * S3];

            if (q < 2) {
                const u16* xp = xbf + (size_t)node * 64 + q * 32;
                *(short8*)&crow[q * 32]      = *(const short8*)xp;
                *(short8*)&crow[q * 32 + 8]  = *(const short8*)(xp + 8);
                *(short8*)&crow[q * 32 + 16] = *(const short8*)(xp + 16);
                *(short8*)&crow[q * 32 + 24] = *(const short8*)(xp + 24);
            } else {
                const int p = q - 2;
                const float inv = 1.0f / ((float)hist[node] + 1e-8f);
                const float* ap = agg + (size_t)node * 64 + p * 32;
                #pragma unroll
                for (int gi = 0; gi < 4; ++gi) {
                    const float4 v0 = *(const float4*)(ap + gi * 8);
                    const float4 v1 = *(const float4*)(ap + gi * 8 + 4);
                    short8 o;
                    o[0] = (short)f2bf(v0.x * inv);
                    o[1] = (short)f2bf(v0.y * inv);
                    o[2] = (short)f2bf(v0.z * inv);
                    o[3] = (short)f2bf(v0.w * inv);
                    o[4] = (short)f2bf(v1.x * inv);
                    o[5] = (short)f2bf(v1.y * inv);
                    o[6] = (short)f2bf(v1.z * inv);
                    o[7] = (short)f2bf(v1.w * inv);
                    *(short8*)&crow[64 + p * 32 + gi * 8] = o;
                }
            }
            LDS_FENCE();

            short8 af[4];
            #pragma unroll
            for (int kk = 0; kk < 4; ++kk)
                af[kk] = *(const short8*)&sm.n.Cs[wid][c * S3 + kk * 32 + q * 8];

            float y[4][4];
            float s[4]  = {0.f, 0.f, 0.f, 0.f};
            float ss[4] = {0.f, 0.f, 0.f, 0.f};
            #pragma unroll
            for (int nn = 0; nn < 4; ++nn) {
                floatx4 acc = MFMA16(af[0], w3f[0][nn], zero);
                acc = MFMA16(af[1], w3f[1][nn], acc);
                acc = MFMA16(af[2], w3f[2][nn], acc);
                acc = MFMA16(af[3], w3f[3][nn], acc);
                #pragma unroll
                for (int r = 0; r < 4; ++r) {
                    const float upd = fmaxf(acc[r] + b3v[nn], 0.f);
                    const float xv = bf2f(sm.n.Cs[wid][(q * 4 + r) * S3 + nn * 16 + c]);
                    const float yy = upd + xv;
                    y[r][nn] = yy;
                    s[r] += yy;
                    ss[r] += yy * yy;
                }
            }

            #pragma unroll
            for (int r = 0; r < 4; ++r) {
                float sr = s[r], sq = ss[r];
                #pragma unroll
                for (int off = 1; off < 16; off <<= 1) {
                    sr += __shfl_xor(sr, off);
                    sq += __shfl_xor(sq, off);
                }
                const float mu  = sr * (1.0f / 64.0f);
                const float var = sq * (1.0f / 64.0f) - mu * mu;
                const float rs  = rsqrtf(var + 1e-5f);
                float* op = out + (size_t)(n0 + q * 4 + r) * 64 + c;
                #pragma unroll
                for (int nn = 0; nn < 4; ++nn)
                    op[nn * 16] = (y[r][nn] - mu) * rs * gv[nn] + bv[nn];
            }
        }
    }
}

extern "C" void kernel_launch(void* const* d_in, const int* in_sizes, int n_in,
                              void* d_out, int out_size, void* d_ws, size_t ws_size,
                              hipStream_t stream) {
    const float* x   = (const float*)d_in[0];
    const int*   ei  = (const int*)d_in[1];
    const float* ef  = (const float*)d_in[2];
    const float* w1  = (const float*)d_in[3];
    const float* b1  = (const float*)d_in[4];
    const float* w2  = (const float*)d_in[5];
    const float* b2  = (const float*)d_in[6];
    const float* w3  = (const float*)d_in[7];
    const float* b3  = (const float*)d_in[8];
    const float* g   = (const float*)d_in[9];
    const float* bb  = (const float*)d_in[10];
    int* ws  = (int*)d_ws;
    float* out = (float*)d_out;

    int maxb = 4;
    hipOccupancyMaxActiveBlocksPerMultiprocessor(&maxb, fused_kernel, 256, 0);
    if (maxb < 1) maxb = 1;
    int grid = maxb * 256;           // 256 CUs on MI355X
    if (grid > 1280) grid = 1280;
    if (grid < 256) grid = 256;      // scan phase needs >= 196 blocks

    void* args[] = { (void*)&x, (void*)&ei, (void*)&ef, (void*)&w1, (void*)&b1,
                     (void*)&w2, (void*)&b2, (void*)&w3, (void*)&b3, (void*)&g,
                     (void*)&bb, (void*)&ws, (void*)&out };
    hipLaunchCooperativeKernel((void*)fused_kernel, dim3(grid), dim3(256),
                               args, 0, stream);
}

// Round 10
// 486.117 us; speedup vs baseline: 1.3855x; 1.0609x over previous
//
#include <hip/hip_runtime.h>
#include <hip/hip_cooperative_groups.h>

namespace cg = cooperative_groups;

typedef unsigned short u16;
typedef unsigned int u32;
typedef short short8 __attribute__((ext_vector_type(8)));
typedef short short4v __attribute__((ext_vector_type(4)));
typedef float floatx4 __attribute__((ext_vector_type(4)));

#define NE 800000
#define NNODES 50000
#define NBLK 196  // ceil(50000/256)

#define LDS_FENCE() __asm__ volatile("s_waitcnt lgkmcnt(0)" ::: "memory")

__device__ __forceinline__ u16 f2bf(float f) {
    union { float f; unsigned int i; } v; v.f = f;
    return (u16)((v.i + 0x7fffu + ((v.i >> 16) & 1u)) >> 16);
}
__device__ __forceinline__ float bf2f(u16 u) {
    union { unsigned int i; float f; } v; v.i = ((unsigned int)u) << 16; return v.f;
}
__device__ __forceinline__ short8 ld8_bf(const float* __restrict__ p) {
    const float4 a = *(const float4*)p;
    const float4 b = *(const float4*)(p + 4);
    short8 o;
    o[0] = (short)f2bf(a.x); o[1] = (short)f2bf(a.y);
    o[2] = (short)f2bf(a.z); o[3] = (short)f2bf(a.w);
    o[4] = (short)f2bf(b.x); o[5] = (short)f2bf(b.y);
    o[6] = (short)f2bf(b.z); o[7] = (short)f2bf(b.w);
    return o;
}

#define MFMA16(a, b, c) __builtin_amdgcn_mfma_f32_16x16x32_bf16(a, b, c, 0, 0, 0)

// LDS: phases overlay. edge=31.0 KB, node=17.4 KB, scan tiny.
union SMem {
    struct {
        u16 A1[4][16 * 104];   // 13312 B
        u16 Hs[4][16 * 72];    //  9216 B
        u16 W2f[2][4][64 * 8]; //  8192 B
        int Ds[4][16];         //   256 B
    } e;
    struct {
        u16 Cs[4][16 * 136];   // 17408 B
    } n;
    struct {
        int ws[4];
        int bsx[256];          // per-block copy of scanned block sums (phase 4)
    } s;
};

// (256,1): min 1 wave/EU -> VGPR cap lifted. Plain (256) pegged VGPR at 96
// (LDS 31.25KB -> 5 waves/EU budget) and spilled the edge K-loop
// (WRITE_SIZE 132 MB, 552 us). (256,4) forced 64 -> worse (171 MB, 906 us).
__global__ __launch_bounds__(256, 1) void fused_kernel(
    const float* __restrict__ x, const int* __restrict__ ei,
    const float* __restrict__ ef, const float* __restrict__ w1,
    const float* __restrict__ b1, const float* __restrict__ w2,
    const float* __restrict__ b2, const float* __restrict__ w3,
    const float* __restrict__ b3, const float* __restrict__ g,
    const float* __restrict__ bb, int* __restrict__ ws_base,
    float* __restrict__ out)
{
    cg::grid_group grid = cg::this_grid();
    __shared__ SMem sm;

    // ws layout (u32 units): agg[3.2M] | hist[50k] | cursor[50k] | bsum[256]
    //                        | bsumx[256] | xbf[1.6M] | sde[1.6M]
    float* agg   = (float*)ws_base;
    int* hist    = ws_base + 3200000;
    int* cursor  = hist + NNODES;
    int* bsum    = cursor + NNODES;
    u16* xbf     = (u16*)(bsum + 512);
    uint2* sde   = (uint2*)(ws_base + 4900512);

    const int tid  = blockIdx.x * 256 + threadIdx.x;
    const int nthr = gridDim.x * 256;
    const int wid  = threadIdx.x >> 6;
    const int lane = threadIdx.x & 63;
    const int q    = lane >> 4;
    const int c    = lane & 15;

    // ---------------- phase 0: zero hist only (50k ints)
    {
        int4* hb = (int4*)hist;
        const int4 z4 = {0, 0, 0, 0};
        for (int i = tid; i < NNODES / 4; i += nthr) hb[i] = z4;
    }
    grid.sync();

    // ---------------- phase 1: dst histogram + x->bf16 + zero agg
    for (int i = tid; i < NE; i += nthr) atomicAdd(&hist[ei[NE + i]], 1);
    for (int i = tid; i < NNODES * 8; i += nthr)
        *(short8*)&xbf[(size_t)i * 8] = ld8_bf(x + (size_t)i * 8);
    {
        float4* ab = (float4*)agg;
        const float4 z4 = {0.f, 0.f, 0.f, 0.f};
        for (int i = tid; i < NNODES * 16; i += nthr) ab[i] = z4;  // 3.2M floats
    }
    grid.sync();

    // ---------------- phase 2: per-chunk exclusive scan (first NBLK blocks)
    // cursor[i] = chunk-local exclusive prefix; bsum[blk] = chunk total
    if (blockIdx.x < NBLK) {
        const int i = blockIdx.x * 256 + threadIdx.x;
        const int v = (i < NNODES) ? hist[i] : 0;
        int inc = v;
        #pragma unroll
        for (int o = 1; o < 64; o <<= 1) {
            const int tt = __shfl_up(inc, o);
            if (lane >= o) inc += tt;
        }
        if (lane == 63) sm.s.ws[wid] = inc;
        __syncthreads();
        int add = 0;
        for (int j = 0; j < wid; ++j) add += sm.s.ws[j];
        const int excl = inc - v + add;
        if (i < NNODES) cursor[i] = excl;
        if (threadIdx.x == 255) bsum[blockIdx.x] = excl + v;
    }
    grid.sync();

    // ---------------- phase 4: scatter packed records (dst-sorted)
    // Every block redundantly scans bsum[0..NBLK) into LDS (saves a grid.sync)
    {
        const int v = (threadIdx.x < NBLK) ? bsum[threadIdx.x] : 0;
        int inc = v;
        #pragma unroll
        for (int o = 1; o < 64; o <<= 1) {
            const int tt = __shfl_up(inc, o);
            if (lane >= o) inc += tt;
        }
        if (lane == 63) sm.s.ws[wid] = inc;
        __syncthreads();
        int add = 0;
        for (int j = 0; j < wid; ++j) add += sm.s.ws[j];
        sm.s.bsx[threadIdx.x] = inc - v + add;
        __syncthreads();

        for (int e = tid; e < NE; e += nthr) {
            const int dst = ei[NE + e];
            const int p = atomicAdd(&cursor[dst], 1) + sm.s.bsx[dst >> 8];
            uint2 v2;
            v2.x = (u32)e;
            v2.y = ((u32)ei[e] << 16) | (u32)dst;
            sde[p] = v2;
        }
    }
    grid.sync();

    // ---------------- phase 5: edge MLP + segmented aggregate
    {
        constexpr int S1 = 104;
        constexpr int S2 = 72;
        const int r4 = lane >> 2;
        const int p4 = lane & 3;

        // W1 B-frags in registers. B[k][n]: n=16*nn+c, k=32*kk+q*8+j
        short8 w1f[3][4];
        #pragma unroll
        for (int kk = 0; kk < 3; ++kk)
            #pragma unroll
            for (int nn = 0; nn < 4; ++nn)
                #pragma unroll
                for (int j = 0; j < 8; ++j) {
                    const int k = kk * 32 + q * 8 + j;
                    w1f[kk][nn][j] = (k < 80) ? (short)f2bf(w1[k * 64 + nn * 16 + c]) : (short)0;
                }
        // W2 B-frags into LDS once
        if (wid == 0) {
            #pragma unroll
            for (int kk = 0; kk < 2; ++kk)
                #pragma unroll
                for (int nn = 0; nn < 4; ++nn) {
                    short8 f;
                    #pragma unroll
                    for (int j = 0; j < 8; ++j) {
                        const int k = kk * 32 + q * 8 + j;
                        f[j] = (short)f2bf(w2[k * 64 + nn * 16 + c]);
                    }
                    *(short8*)&sm.e.W2f[kk][nn][lane * 8] = f;
                }
        }
        float b1v[4], b2v[4];
        #pragma unroll
        for (int nn = 0; nn < 4; ++nn) {
            b1v[nn] = b1[nn * 16 + c];
            b2v[nn] = b2[nn * 16 + c];
        }
        __syncthreads();
        // zero pad region (cols 80..96) once
        if (q == 1) {
            const short8 z8 = {0, 0, 0, 0, 0, 0, 0, 0};
            *(short8*)&sm.e.A1[wid][c * S1 + 80] = z8;
            *(short8*)&sm.e.A1[wid][c * S1 + 88] = z8;
        }

        const floatx4 zero = {0.f, 0.f, 0.f, 0.f};
        const int ntile = NE / 16;  // 50000
        const int stride = gridDim.x * 4;
        int t = blockIdx.x * 4 + wid;

        // prologue: idx for t and t+stride, data for t
        uint2 sdB; u32 eB;
        short8 xa, xb; float4 ev;
        int dcur;
        {
            const uint2 sdA = sde[t * 16 + c];
            const u32  eA  = sde[t * 16 + r4].x;
            dcur = (int)(sdA.y & 0xffffu);
            const int sA = (int)(sdA.y >> 16);
            int tb = t + stride; if (tb >= ntile) tb = ntile - 1;
            sdB = sde[tb * 16 + c];
            eB  = sde[tb * 16 + r4].x;
            const u16* xp = xbf + (size_t)sA * 64 + q * 16;
            xa = *(const short8*)xp;
            xb = *(const short8*)(xp + 8);
            ev = *(const float4*)(ef + (size_t)eA * 16 + p4 * 4);
        }

        for (; t < ntile; t += stride) {
            u16* arow = &sm.e.A1[wid][c * S1 + q * 16];
            *(short8*)arow       = xa;
            *(short8*)(arow + 8) = xb;
            {
                short4v e4;
                e4[0] = (short)f2bf(ev.x); e4[1] = (short)f2bf(ev.y);
                e4[2] = (short)f2bf(ev.z); e4[3] = (short)f2bf(ev.w);
                *(short4v*)&sm.e.A1[wid][r4 * S1 + 64 + p4 * 4] = e4;
            }
            if (q == 0) sm.e.Ds[wid][c] = dcur;
            LDS_FENCE();

            short8 a1k[3];
            #pragma unroll
            for (int kk = 0; kk < 3; ++kk)
                a1k[kk] = *(const short8*)&sm.e.A1[wid][c * S1 + kk * 32 + q * 8];

            // prefetch data for t+stride
            const int dnext = (int)(sdB.y & 0xffffu);
            {
                const int sN = (int)(sdB.y >> 16);
                const u16* xp = xbf + (size_t)sN * 64 + q * 16;
                xa = *(const short8*)xp;
                xb = *(const short8*)(xp + 8);
                ev = *(const float4*)(ef + (size_t)eB * 16 + p4 * 4);
            }
            {
                int tb = t + 2 * stride; if (tb >= ntile) tb = ntile - 1;
                sdB = sde[tb * 16 + c];
                eB  = sde[tb * 16 + r4].x;
            }

            // GEMM1 + bias + relu -> Hs
            #pragma unroll
            for (int nn = 0; nn < 4; ++nn) {
                floatx4 acc = MFMA16(a1k[0], w1f[0][nn], zero);
                acc = MFMA16(a1k[1], w1f[1][nn], acc);
                acc = MFMA16(a1k[2], w1f[2][nn], acc);
                #pragma unroll
                for (int r = 0; r < 4; ++r) {
                    const float h = fmaxf(acc[r] + b1v[nn], 0.f);
                    sm.e.Hs[wid][(q * 4 + r) * S2 + nn * 16 + c] = f2bf(h);
                }
            }
            LDS_FENCE();

            short8 a2k[2];
            #pragma unroll
            for (int kk = 0; kk < 2; ++kk)
                a2k[kk] = *(const short8*)&sm.e.Hs[wid][c * S2 + kk * 32 + q * 8];

            // GEMM2 -> msg (bf16) overlaid into Hs
            #pragma unroll
            for (int nn = 0; nn < 4; ++nn) {
                const short8 wf0 = *(const short8*)&sm.e.W2f[0][nn][lane * 8];
                const short8 wf1 = *(const short8*)&sm.e.W2f[1][nn][lane * 8];
                floatx4 mg = MFMA16(a2k[0], wf0, zero);
                mg = MFMA16(a2k[1], wf1, mg);
                #pragma unroll
                for (int r = 0; r < 4; ++r)
                    sm.e.Hs[wid][(q * 4 + r) * S2 + nn * 16 + c] = f2bf(mg[r] + b2v[nn]);
            }
            LDS_FENCE();

            // segmented reduction over sorted dst (lane = column)
            int dc = sm.e.Ds[wid][0];
            float acc = bf2f(sm.e.Hs[wid][lane]);
            #pragma unroll
            for (int row = 1; row < 16; ++row) {
                const int d = sm.e.Ds[wid][row];
                const float v = bf2f(sm.e.Hs[wid][row * S2 + lane]);
                if (d == dc) {
                    acc += v;
                } else {
                    atomicAdd(&agg[(size_t)dc * 64 + lane], acc);
                    dc = d;
                    acc = v;
                }
            }
            atomicAdd(&agg[(size_t)dc * 64 + lane], acc);

            dcur = dnext;
        }
    }
    grid.sync();

    // ---------------- phase 6: node update + LayerNorm
    {
        constexpr int S3 = 136;

        short8 w3f[4][4];
        #pragma unroll
        for (int kk = 0; kk < 4; ++kk)
            #pragma unroll
            for (int nn = 0; nn < 4; ++nn)
                #pragma unroll
                for (int j = 0; j < 8; ++j) {
                    const int k = kk * 32 + q * 8 + j;
                    w3f[kk][nn][j] = (short)f2bf(w3[k * 64 + nn * 16 + c]);
                }
        float b3v[4], gv[4], bv[4];
        #pragma unroll
        for (int nn = 0; nn < 4; ++nn) {
            b3v[nn] = b3[nn * 16 + c];
            gv[nn]  = g[nn * 16 + c];
            bv[nn]  = bb[nn * 16 + c];
        }

        const floatx4 zero = {0.f, 0.f, 0.f, 0.f};
        const int ntile = NNODES / 16;  // 3125

        for (int t = blockIdx.x * 4 + wid; t < ntile; t += gridDim.x * 4) {
            const int n0 = t * 16;
            const int node = n0 + c;
            u16* crow = &sm.n.Cs[wid][c * S3];

            if (q < 2) {
                const u16* xp = xbf + (size_t)node * 64 + q * 32;
                *(short8*)&crow[q * 32]      = *(const short8*)xp;
                *(short8*)&crow[q * 32 + 8]  = *(const short8*)(xp + 8);
                *(short8*)&crow[q * 32 + 16] = *(const short8*)(xp + 16);
                *(short8*)&crow[q * 32 + 24] = *(const short8*)(xp + 24);
            } else {
                const int p = q - 2;
                const float inv = 1.0f / ((float)hist[node] + 1e-8f);
                const float* ap = agg + (size_t)node * 64 + p * 32;
                #pragma unroll
                for (int gi = 0; gi < 4; ++gi) {
                    const float4 v0 = *(const float4*)(ap + gi * 8);
                    const float4 v1 = *(const float4*)(ap + gi * 8 + 4);
                    short8 o;
                    o[0] = (short)f2bf(v0.x * inv);
                    o[1] = (short)f2bf(v0.y * inv);
                    o[2] = (short)f2bf(v0.z * inv);
                    o[3] = (short)f2bf(v0.w * inv);
                    o[4] = (short)f2bf(v1.x * inv);
                    o[5] = (short)f2bf(v1.y * inv);
                    o[6] = (short)f2bf(v1.z * inv);
                    o[7] = (short)f2bf(v1.w * inv);
                    *(short8*)&crow[64 + p * 32 + gi * 8] = o;
                }
            }
            LDS_FENCE();

            short8 af[4];
            #pragma unroll
            for (int kk = 0; kk < 4; ++kk)
                af[kk] = *(const short8*)&sm.n.Cs[wid][c * S3 + kk * 32 + q * 8];

            float y[4][4];
            float s[4]  = {0.f, 0.f, 0.f, 0.f};
            float ss[4] = {0.f, 0.f, 0.f, 0.f};
            #pragma unroll
            for (int nn = 0; nn < 4; ++nn) {
                floatx4 acc = MFMA16(af[0], w3f[0][nn], zero);
                acc = MFMA16(af[1], w3f[1][nn], acc);
                acc = MFMA16(af[2], w3f[2][nn], acc);
                acc = MFMA16(af[3], w3f[3][nn], acc);
                #pragma unroll
                for (int r = 0; r < 4; ++r) {
                    const float upd = fmaxf(acc[r] + b3v[nn], 0.f);
                    const float xv = bf2f(sm.n.Cs[wid][(q * 4 + r) * S3 + nn * 16 + c]);
                    const float yy = upd + xv;
                    y[r][nn] = yy;
                    s[r] += yy;
                    ss[r] += yy * yy;
                }
            }

            #pragma unroll
            for (int r = 0; r < 4; ++r) {
                float sr = s[r], sq = ss[r];
                #pragma unroll
                for (int off = 1; off < 16; off <<= 1) {
                    sr += __shfl_xor(sr, off);
                    sq += __shfl_xor(sq, off);
                }
                const float mu  = sr * (1.0f / 64.0f);
                const float var = sq * (1.0f / 64.0f) - mu * mu;
                const float rs  = rsqrtf(var + 1e-5f);
                float* op = out + (size_t)(n0 + q * 4 + r) * 64 + c;
                #pragma unroll
                for (int nn = 0; nn < 4; ++nn)
                    op[nn * 16] = (y[r][nn] - mu) * rs * gv[nn] + bv[nn];
            }
        }
    }
}

extern "C" void kernel_launch(void* const* d_in, const int* in_sizes, int n_in,
                              void* d_out, int out_size, void* d_ws, size_t ws_size,
                              hipStream_t stream) {
    const float* x   = (const float*)d_in[0];
    const int*   ei  = (const int*)d_in[1];
    const float* ef  = (const float*)d_in[2];
    const float* w1  = (const float*)d_in[3];
    const float* b1  = (const float*)d_in[4];
    const float* w2  = (const float*)d_in[5];
    const float* b2  = (const float*)d_in[6];
    const float* w3  = (const float*)d_in[7];
    const float* b3  = (const float*)d_in[8];
    const float* g   = (const float*)d_in[9];
    const float* bb  = (const float*)d_in[10];
    int* ws  = (int*)d_ws;
    float* out = (float*)d_out;

    int maxb = 4;
    hipOccupancyMaxActiveBlocksPerMultiprocessor(&maxb, fused_kernel, 256, 0);
    if (maxb < 1) maxb = 1;
    int grid = maxb * 256;           // 256 CUs on MI355X
    if (grid > 1280) grid = 1280;
    if (grid < 256) grid = 256;      // scan phase needs >= 196 blocks

    void* args[] = { (void*)&x, (void*)&ei, (void*)&ef, (void*)&w1, (void*)&b1,
                     (void*)&w2, (void*)&b2, (void*)&w3, (void*)&b3, (void*)&g,
                     (void*)&bb, (void*)&ws, (void*)&out };
    hipLaunchCooperativeKernel((void*)fused_kernel, dim3(grid), dim3(256),
                               args, 0, stream);
}

// Round 11
// 473.315 us; speedup vs baseline: 1.4230x; 1.0270x over previous
//
#include <hip/hip_runtime.h>
#include <hip/hip_cooperative_groups.h>

namespace cg = cooperative_groups;

typedef unsigned short u16;
typedef unsigned int u32;
typedef short short8 __attribute__((ext_vector_type(8)));
typedef short short4v __attribute__((ext_vector_type(4)));
typedef float floatx4 __attribute__((ext_vector_type(4)));

#define NE 800000
#define NNODES 50000
#define NBLK 196  // ceil(50000/256)

#define LDS_FENCE() __asm__ volatile("s_waitcnt lgkmcnt(0)" ::: "memory")

__device__ __forceinline__ u16 f2bf(float f) {
    union { float f; unsigned int i; } v; v.f = f;
    return (u16)((v.i + 0x7fffu + ((v.i >> 16) & 1u)) >> 16);
}
__device__ __forceinline__ float bf2f(u16 u) {
    union { unsigned int i; float f; } v; v.i = ((unsigned int)u) << 16; return v.f;
}
__device__ __forceinline__ short8 ld8_bf(const float* __restrict__ p) {
    const float4 a = *(const float4*)p;
    const float4 b = *(const float4*)(p + 4);
    short8 o;
    o[0] = (short)f2bf(a.x); o[1] = (short)f2bf(a.y);
    o[2] = (short)f2bf(a.z); o[3] = (short)f2bf(a.w);
    o[4] = (short)f2bf(b.x); o[5] = (short)f2bf(b.y);
    o[6] = (short)f2bf(b.z); o[7] = (short)f2bf(b.w);
    return o;
}

#define MFMA16(a, b, c) __builtin_amdgcn_mfma_f32_16x16x32_bf16(a, b, c, 0, 0, 0)

// ---------------------------------------------------------------------------
// Aux cooperative kernel: zero -> hist + x->bf16 + zero agg -> scan1 ->
// scatter (with redundant in-LDS scan of block sums). Register-light; the
// register-hungry edge loop stays in its own kernel (r8-r10 lesson: fused
// edge loop spills at the allocator's LDS-derived VGPR cap).
// ---------------------------------------------------------------------------
__global__ __launch_bounds__(256) void aux_kernel(
    const float* __restrict__ x, const int* __restrict__ ei,
    int* __restrict__ ws_base)
{
    cg::grid_group grid = cg::this_grid();
    __shared__ int ws[4];
    __shared__ int bsx[256];

    float* agg   = (float*)ws_base;
    int* hist    = ws_base + 3200000;
    int* cursor  = hist + NNODES;
    int* bsum    = cursor + NNODES;
    u16* xbf     = (u16*)(bsum + 512);
    uint2* sde   = (uint2*)(ws_base + 4900512);

    const int tid  = blockIdx.x * 256 + threadIdx.x;
    const int nthr = gridDim.x * 256;
    const int wid  = threadIdx.x >> 6;
    const int lane = threadIdx.x & 63;

    // phase 0: zero hist (50k ints)
    {
        int4* hb = (int4*)hist;
        const int4 z4 = {0, 0, 0, 0};
        for (int i = tid; i < NNODES / 4; i += nthr) hb[i] = z4;
    }
    grid.sync();

    // phase 1: dst histogram + x->bf16 + zero agg
    for (int i = tid; i < NE; i += nthr) atomicAdd(&hist[ei[NE + i]], 1);
    for (int i = tid; i < NNODES * 8; i += nthr)
        *(short8*)&xbf[(size_t)i * 8] = ld8_bf(x + (size_t)i * 8);
    {
        float4* ab = (float4*)agg;
        const float4 z4 = {0.f, 0.f, 0.f, 0.f};
        for (int i = tid; i < NNODES * 16; i += nthr) ab[i] = z4;
    }
    grid.sync();

    // phase 2: per-chunk exclusive scan (first NBLK blocks)
    if (blockIdx.x < NBLK) {
        const int i = blockIdx.x * 256 + threadIdx.x;
        const int v = (i < NNODES) ? hist[i] : 0;
        int inc = v;
        #pragma unroll
        for (int o = 1; o < 64; o <<= 1) {
            const int tt = __shfl_up(inc, o);
            if (lane >= o) inc += tt;
        }
        if (lane == 63) ws[wid] = inc;
        __syncthreads();
        int add = 0;
        for (int j = 0; j < wid; ++j) add += ws[j];
        const int excl = inc - v + add;
        if (i < NNODES) cursor[i] = excl;
        if (threadIdx.x == 255) bsum[blockIdx.x] = excl + v;
    }
    grid.sync();

    // phase 3: scatter; every block redundantly scans bsum into LDS
    {
        const int v = (threadIdx.x < NBLK) ? bsum[threadIdx.x] : 0;
        int inc = v;
        #pragma unroll
        for (int o = 1; o < 64; o <<= 1) {
            const int tt = __shfl_up(inc, o);
            if (lane >= o) inc += tt;
        }
        if (lane == 63) ws[wid] = inc;
        __syncthreads();
        int add = 0;
        for (int j = 0; j < wid; ++j) add += ws[j];
        bsx[threadIdx.x] = inc - v + add;
        __syncthreads();

        for (int e = tid; e < NE; e += nthr) {
            const int dst = ei[NE + e];
            const int p = atomicAdd(&cursor[dst], 1) + bsx[dst >> 8];
            uint2 v2;
            v2.x = (u32)e;
            v2.y = ((u32)ei[e] << 16) | (u32)dst;
            sde[p] = v2;
        }
    }
}

// ---------------------------------------------------------------------------
// Edge kernel (r7-proven: 84 VGPR, no spill, ~81us), software-pipelined,
// dst-sorted via sde records; segmented per-wave reduction -> ~2 atomics/lane
// ---------------------------------------------------------------------------
__global__ __launch_bounds__(256) void edge_kernel(
    const u16* __restrict__ xbf, const float* __restrict__ ef,
    const float* __restrict__ w1, const float* __restrict__ b1,
    const float* __restrict__ w2, const float* __restrict__ b2,
    const uint2* __restrict__ sde, float* __restrict__ agg)
{
    constexpr int S1 = 104;  // A1 row stride (bf16): pad 96->104
    constexpr int S2 = 72;   // h/msg row stride: pad 64->72
    __shared__ u16 A1[4][16 * S1];
    __shared__ u16 Hs[4][16 * S2];
    __shared__ int Ds[4][16];
    __shared__ u16 W2f[2][4][64 * 8];  // per-lane W2 B-frags (8 KB)

    const int wid  = threadIdx.x >> 6;
    const int lane = threadIdx.x & 63;
    const int q    = lane >> 4;   // quad
    const int c    = lane & 15;   // col within quad
    const int r4   = lane >> 2;   // ef row handled by this lane
    const int p4   = lane & 3;    // ef float4 part

    // W1 B-frags in registers. B[k][n]: n=16*nn+c, k=32*kk+q*8+j
    short8 w1f[3][4];
    #pragma unroll
    for (int kk = 0; kk < 3; ++kk)
        #pragma unroll
        for (int nn = 0; nn < 4; ++nn)
            #pragma unroll
            for (int j = 0; j < 8; ++j) {
                const int k = kk * 32 + q * 8 + j;
                w1f[kk][nn][j] = (k < 80) ? (short)f2bf(w1[k * 64 + nn * 16 + c]) : (short)0;
            }
    // W2 B-frags into LDS once
    if (wid == 0) {
        #pragma unroll
        for (int kk = 0; kk < 2; ++kk)
            #pragma unroll
            for (int nn = 0; nn < 4; ++nn) {
                short8 f;
                #pragma unroll
                for (int j = 0; j < 8; ++j) {
                    const int k = kk * 32 + q * 8 + j;
                    f[j] = (short)f2bf(w2[k * 64 + nn * 16 + c]);
                }
                *(short8*)&W2f[kk][nn][lane * 8] = f;
            }
    }
    float b1v[4], b2v[4];
    #pragma unroll
    for (int nn = 0; nn < 4; ++nn) {
        b1v[nn] = b1[nn * 16 + c];
        b2v[nn] = b2[nn * 16 + c];
    }
    // zero pad region (cols 80..96) once — never overwritten
    if (q == 1) {
        const short8 z8 = {0, 0, 0, 0, 0, 0, 0, 0};
        *(short8*)&A1[wid][c * S1 + 80] = z8;
        *(short8*)&A1[wid][c * S1 + 88] = z8;
    }
    __syncthreads();

    const floatx4 zero = {0.f, 0.f, 0.f, 0.f};
    const int ntile = NE / 16;  // 50000
    const int stride = gridDim.x * 4;
    int t = blockIdx.x * 4 + wid;

    // prologue: idx for t and t+stride, data for t
    uint2 sdB; u32 eB;
    short8 xa, xb; float4 ev;
    int dcur;
    {
        const uint2 sdA = sde[t * 16 + c];
        const u32  eA  = sde[t * 16 + r4].x;
        dcur = (int)(sdA.y & 0xffffu);
        const int sA = (int)(sdA.y >> 16);
        int tb = t + stride; if (tb >= ntile) tb = ntile - 1;
        sdB = sde[tb * 16 + c];
        eB  = sde[tb * 16 + r4].x;
        const u16* xp = xbf + (size_t)sA * 64 + q * 16;
        xa = *(const short8*)xp;
        xb = *(const short8*)(xp + 8);
        ev = *(const float4*)(ef + (size_t)eA * 16 + p4 * 4);
    }

    for (; t < ntile; t += stride) {
        u16* arow = &A1[wid][c * S1 + q * 16];
        *(short8*)arow       = xa;
        *(short8*)(arow + 8) = xb;
        {
            short4v e4;
            e4[0] = (short)f2bf(ev.x); e4[1] = (short)f2bf(ev.y);
            e4[2] = (short)f2bf(ev.z); e4[3] = (short)f2bf(ev.w);
            *(short4v*)&A1[wid][r4 * S1 + 64 + p4 * 4] = e4;
        }
        if (q == 0) Ds[wid][c] = dcur;
        LDS_FENCE();

        short8 a1k[3];
        #pragma unroll
        for (int kk = 0; kk < 3; ++kk)
            a1k[kk] = *(const short8*)&A1[wid][c * S1 + kk * 32 + q * 8];

        // prefetch data for t+stride
        const int dnext = (int)(sdB.y & 0xffffu);
        {
            const int sN = (int)(sdB.y >> 16);
            const u16* xp = xbf + (size_t)sN * 64 + q * 16;
            xa = *(const short8*)xp;
            xb = *(const short8*)(xp + 8);
            ev = *(const float4*)(ef + (size_t)eB * 16 + p4 * 4);
        }
        {
            int tb = t + 2 * stride; if (tb >= ntile) tb = ntile - 1;
            sdB = sde[tb * 16 + c];
            eB  = sde[tb * 16 + r4].x;
        }

        // GEMM1 + bias + relu -> Hs
        #pragma unroll
        for (int nn = 0; nn < 4; ++nn) {
            floatx4 acc = MFMA16(a1k[0], w1f[0][nn], zero);
            acc = MFMA16(a1k[1], w1f[1][nn], acc);
            acc = MFMA16(a1k[2], w1f[2][nn], acc);
            #pragma unroll
            for (int r = 0; r < 4; ++r) {
                const float h = fmaxf(acc[r] + b1v[nn], 0.f);
                Hs[wid][(q * 4 + r) * S2 + nn * 16 + c] = f2bf(h);
            }
        }
        LDS_FENCE();

        short8 a2k[2];
        #pragma unroll
        for (int kk = 0; kk < 2; ++kk)
            a2k[kk] = *(const short8*)&Hs[wid][c * S2 + kk * 32 + q * 8];

        // GEMM2 -> msg (bf16) overlaid into Hs
        #pragma unroll
        for (int nn = 0; nn < 4; ++nn) {
            const short8 wf0 = *(const short8*)&W2f[0][nn][lane * 8];
            const short8 wf1 = *(const short8*)&W2f[1][nn][lane * 8];
            floatx4 mg = MFMA16(a2k[0], wf0, zero);
            mg = MFMA16(a2k[1], wf1, mg);
            #pragma unroll
            for (int r = 0; r < 4; ++r)
                Hs[wid][(q * 4 + r) * S2 + nn * 16 + c] = f2bf(mg[r] + b2v[nn]);
        }
        LDS_FENCE();

        // segmented reduction over sorted dst (lane = column)
        int dc = Ds[wid][0];
        float acc = bf2f(Hs[wid][lane]);
        #pragma unroll
        for (int row = 1; row < 16; ++row) {
            const int d = Ds[wid][row];
            const float v = bf2f(Hs[wid][row * S2 + lane]);
            if (d == dc) {
                acc += v;
            } else {
                atomicAdd(&agg[(size_t)dc * 64 + lane], acc);
                dc = d;
                acc = v;
            }
        }
        atomicAdd(&agg[(size_t)dc * 64 + lane], acc);

        dcur = dnext;
    }
}

// ---------------------------------------------------------------------------
// Node kernel (r7): cat = [xbf | bf16(agg/cnt)]; relu(cat@W3+b3)+x; LayerNorm
// ---------------------------------------------------------------------------
__global__ __launch_bounds__(256) void node_kernel(
    const u16* __restrict__ xbf, const float* __restrict__ w3,
    const float* __restrict__ b3, const float* __restrict__ g,
    const float* __restrict__ bb, const float* __restrict__ agg,
    const int* __restrict__ hist, float* __restrict__ out)
{
    constexpr int S3 = 136;  // 128 + 8 pad
    __shared__ u16 Cs[4][16 * S3];

    const int wid  = threadIdx.x >> 6;
    const int lane = threadIdx.x & 63;
    const int q    = lane >> 4;
    const int c    = lane & 15;

    short8 w3f[4][4];
    #pragma unroll
    for (int kk = 0; kk < 4; ++kk)
        #pragma unroll
        for (int nn = 0; nn < 4; ++nn)
            #pragma unroll
            for (int j = 0; j < 8; ++j) {
                const int k = kk * 32 + q * 8 + j;
                w3f[kk][nn][j] = (short)f2bf(w3[k * 64 + nn * 16 + c]);
            }
    float b3v[4], gv[4], bv[4];
    #pragma unroll
    for (int nn = 0; nn < 4; ++nn) {
        b3v[nn] = b3[nn * 16 + c];
        gv[nn]  = g[nn * 16 + c];
        bv[nn]  = bb[nn * 16 + c];
    }

    const floatx4 zero = {0.f, 0.f, 0.f, 0.f};
    const int ntile = NNODES / 16;  // 3125

    for (int t = blockIdx.x * 4 + wid; t < ntile; t += gridDim.x * 4) {
        const int n0 = t * 16;
        const int node = n0 + c;
        u16* crow = &Cs[wid][c * S3];

        if (q < 2) {
            const u16* xp = xbf + (size_t)node * 64 + q * 32;
            *(short8*)&crow[q * 32]      = *(const short8*)xp;
            *(short8*)&crow[q * 32 + 8]  = *(const short8*)(xp + 8);
            *(short8*)&crow[q * 32 + 16] = *(const short8*)(xp + 16);
            *(short8*)&crow[q * 32 + 24] = *(const short8*)(xp + 24);
        } else {
            const int p = q - 2;
            const float inv = 1.0f / ((float)hist[node] + 1e-8f);
            const float* ap = agg + (size_t)node * 64 + p * 32;
            #pragma unroll
            for (int gi = 0; gi < 4; ++gi) {
                const float4 v0 = *(const float4*)(ap + gi * 8);
                const float4 v1 = *(const float4*)(ap + gi * 8 + 4);
                short8 o;
                o[0] = (short)f2bf(v0.x * inv);
                o[1] = (short)f2bf(v0.y * inv);
                o[2] = (short)f2bf(v0.z * inv);
                o[3] = (short)f2bf(v0.w * inv);
                o[4] = (short)f2bf(v1.x * inv);
                o[5] = (short)f2bf(v1.y * inv);
                o[6] = (short)f2bf(v1.z * inv);
                o[7] = (short)f2bf(v1.w * inv);
                *(short8*)&crow[64 + p * 32 + gi * 8] = o;
            }
        }
        LDS_FENCE();

        short8 af[4];
        #pragma unroll
        for (int kk = 0; kk < 4; ++kk)
            af[kk] = *(const short8*)&Cs[wid][c * S3 + kk * 32 + q * 8];

        float y[4][4];
        float s[4]  = {0.f, 0.f, 0.f, 0.f};
        float ss[4] = {0.f, 0.f, 0.f, 0.f};
        #pragma unroll
        for (int nn = 0; nn < 4; ++nn) {
            floatx4 acc = MFMA16(af[0], w3f[0][nn], zero);
            acc = MFMA16(af[1], w3f[1][nn], acc);
            acc = MFMA16(af[2], w3f[2][nn], acc);
            acc = MFMA16(af[3], w3f[3][nn], acc);
            #pragma unroll
            for (int r = 0; r < 4; ++r) {
                const float upd = fmaxf(acc[r] + b3v[nn], 0.f);
                const float xv = bf2f(Cs[wid][(q * 4 + r) * S3 + nn * 16 + c]);
                const float yy = upd + xv;
                y[r][nn] = yy;
                s[r] += yy;
                ss[r] += yy * yy;
            }
        }

        #pragma unroll
        for (int r = 0; r < 4; ++r) {
            float sr = s[r], sq = ss[r];
            #pragma unroll
            for (int off = 1; off < 16; off <<= 1) {
                sr += __shfl_xor(sr, off);
                sq += __shfl_xor(sq, off);
            }
            const float mu  = sr * (1.0f / 64.0f);
            const float var = sq * (1.0f / 64.0f) - mu * mu;
            const float rs  = rsqrtf(var + 1e-5f);
            float* op = out + (size_t)(n0 + q * 4 + r) * 64 + c;
            #pragma unroll
            for (int nn = 0; nn < 4; ++nn)
                op[nn * 16] = (y[r][nn] - mu) * rs * gv[nn] + bv[nn];
        }
    }
}

extern "C" void kernel_launch(void* const* d_in, const int* in_sizes, int n_in,
                              void* d_out, int out_size, void* d_ws, size_t ws_size,
                              hipStream_t stream) {
    const float* x   = (const float*)d_in[0];
    const int*   ei  = (const int*)d_in[1];
    const float* ef  = (const float*)d_in[2];
    const float* w1  = (const float*)d_in[3];
    const float* b1  = (const float*)d_in[4];
    const float* w2  = (const float*)d_in[5];
    const float* b2  = (const float*)d_in[6];
    const float* w3  = (const float*)d_in[7];
    const float* b3  = (const float*)d_in[8];
    const float* g   = (const float*)d_in[9];
    const float* bb  = (const float*)d_in[10];
    int* ws = (int*)d_ws;

    // ws layout (u32 units): agg[3.2M] | hist[50k] | cursor[50k] | bsum[512]
    //                        | xbf[1.6M] | sde[1.6M]
    float* agg = (float*)d_ws;
    int* hist  = ws + 3200000;
    u16* xbf   = (u16*)(ws + 3300512);
    uint2* sde = (uint2*)(ws + 4900512);

    int maxb = 8;
    hipOccupancyMaxActiveBlocksPerMultiprocessor(&maxb, aux_kernel, 256, 0);
    if (maxb < 1) maxb = 1;
    int agrid = maxb * 256;
    if (agrid > 512) agrid = 512;
    if (agrid < NBLK) agrid = NBLK;   // scan phase needs >= 196 blocks

    void* args[] = { (void*)&x, (void*)&ei, (void*)&ws };
    hipLaunchCooperativeKernel((void*)aux_kernel, dim3(agrid), dim3(256),
                               args, 0, stream);
    edge_kernel<<<2048, 256, 0, stream>>>(xbf, ef, w1, b1, w2, b2, sde, agg);
    node_kernel<<<782, 256, 0, stream>>>(xbf, w3, b3, g, bb, agg, hist,
                                         (float*)d_out);
}

// Round 12
// 355.936 us; speedup vs baseline: 1.8923x; 1.3298x over previous
//
#include <hip/hip_runtime.h>

typedef unsigned short u16;
typedef unsigned int u32;
typedef short short8 __attribute__((ext_vector_type(8)));
typedef short short4v __attribute__((ext_vector_type(4)));
typedef float floatx4 __attribute__((ext_vector_type(4)));

#define NE 800000
#define NNODES 50000
#define NBUCK 3125   // dst >> 4
#define BCAP 368     // 256 + 7 sigma, multiple of 16

#define LDS_FENCE() __asm__ volatile("s_waitcnt lgkmcnt(0)" ::: "memory")

__device__ __forceinline__ u16 f2bf(float f) {
    union { float f; unsigned int i; } v; v.f = f;
    return (u16)((v.i + 0x7fffu + ((v.i >> 16) & 1u)) >> 16);
}
__device__ __forceinline__ float bf2f(u16 u) {
    union { unsigned int i; float f; } v; v.i = ((unsigned int)u) << 16; return v.f;
}
__device__ __forceinline__ short8 ld8_bf(const float* __restrict__ p) {
    const float4 a = *(const float4*)p;
    const float4 b = *(const float4*)(p + 4);
    short8 o;
    o[0] = (short)f2bf(a.x); o[1] = (short)f2bf(a.y);
    o[2] = (short)f2bf(a.z); o[3] = (short)f2bf(a.w);
    o[4] = (short)f2bf(b.x); o[5] = (short)f2bf(b.y);
    o[6] = (short)f2bf(b.z); o[7] = (short)f2bf(b.w);
    return o;
}

#define MFMA16(a, b, c) __builtin_amdgcn_mfma_f32_16x16x32_bf16(a, b, c, 0, 0, 0)

// ---------------------------------------------------------------------------
// prep: zero agg(50001 rows)+hist+bcur (contiguous) + x->bf16
// ---------------------------------------------------------------------------
__global__ __launch_bounds__(256) void prep_kernel(
    const float* __restrict__ x, int* __restrict__ ws_base)
{
    const int tid  = blockIdx.x * 256 + threadIdx.x;
    const int nthr = gridDim.x * 256;
    int4* zb = (int4*)ws_base;
    const int4 z4 = {0, 0, 0, 0};
    for (int i = tid; i < 825016; i += nthr) zb[i] = z4;  // 3,300,064 ints
    u16* xbf = (u16*)(ws_base + 3300064);
    for (int i = tid; i < NNODES * 8; i += nthr)
        *(short8*)&xbf[(size_t)i * 8] = ld8_bf(x + (size_t)i * 8);
}

// ---------------------------------------------------------------------------
// scatter: record -> bucket slot (NO scan: base = bucket*BCAP), + in-degree
// ---------------------------------------------------------------------------
__global__ __launch_bounds__(256) void scatter_kernel(
    const int* __restrict__ ei, int* __restrict__ hist,
    int* __restrict__ bcur, uint2* __restrict__ sde)
{
    const int e = blockIdx.x * 256 + threadIdx.x;
    if (e < NE) {
        const int dst = ei[NE + e];
        const int src = ei[e];
        atomicAdd(&hist[dst], 1);
        const int b = dst >> 4;
        const int p = atomicAdd(&bcur[b * 16], 1);  // stride-16 padded counters
        if (p < BCAP) {
            uint2 v;
            v.x = (u32)e;
            v.y = ((u32)src << 16) | (u32)(dst & 15);
            sde[(size_t)b * BCAP + p] = v;
        }
    }
}

// ---------------------------------------------------------------------------
// Edge kernel: one wave = one bucket (16 nodes, ~256 edges).
//   1. load bucket records, LDS counting-sort by dst&15 (= full sort by dst)
//   2. per 16-row tile: A1=[xbf[src]|bf16(ef)|pad]; h=relu(A1@W1+b1);
//      msg=h@W2+b2; segmented reduction over sorted dst (~2 atomics/lane/tile)
//   Tail rows: sentinel dst -> scratch agg row NNODES.
// ---------------------------------------------------------------------------
__global__ __launch_bounds__(256) void edge_kernel(
    const u16* __restrict__ xbf, const float* __restrict__ ef,
    const float* __restrict__ w1, const float* __restrict__ b1,
    const float* __restrict__ w2, const float* __restrict__ b2,
    const uint2* __restrict__ sde, const int* __restrict__ bcur,
    float* __restrict__ agg)
{
    constexpr int S1 = 104;  // A1 row stride (bf16): pad 96->104
    constexpr int S2 = 72;   // h/msg row stride: pad 64->72
    __shared__ u16 A1[4][16 * S1];
    __shared__ u16 Hs[4][16 * S2];
    __shared__ int Ds[4][16];
    __shared__ u16 W2f[2][4][64 * 8];  // 8 KB
    __shared__ uint2 srt[4][BCAP];     // sorted records, 11.5 KB
    __shared__ int cnt16[4][16], base16[4][16], ctr16[4][16];

    const int wid  = threadIdx.x >> 6;
    const int lane = threadIdx.x & 63;
    const int q    = lane >> 4;   // quad
    const int c    = lane & 15;   // col within quad
    const int r4   = lane >> 2;   // ef row handled by this lane
    const int p4   = lane & 3;    // ef float4 part

    // W1 B-frags in registers. B[k][n]: n=16*nn+c, k=32*kk+q*8+j
    short8 w1f[3][4];
    #pragma unroll
    for (int kk = 0; kk < 3; ++kk)
        #pragma unroll
        for (int nn = 0; nn < 4; ++nn)
            #pragma unroll
            for (int j = 0; j < 8; ++j) {
                const int k = kk * 32 + q * 8 + j;
                w1f[kk][nn][j] = (k < 80) ? (short)f2bf(w1[k * 64 + nn * 16 + c]) : (short)0;
            }
    if (wid == 0) {
        #pragma unroll
        for (int kk = 0; kk < 2; ++kk)
            #pragma unroll
            for (int nn = 0; nn < 4; ++nn) {
                short8 f;
                #pragma unroll
                for (int j = 0; j < 8; ++j) {
                    const int k = kk * 32 + q * 8 + j;
                    f[j] = (short)f2bf(w2[k * 64 + nn * 16 + c]);
                }
                *(short8*)&W2f[kk][nn][lane * 8] = f;
            }
    }
    float b1v[4], b2v[4];
    #pragma unroll
    for (int nn = 0; nn < 4; ++nn) {
        b1v[nn] = b1[nn * 16 + c];
        b2v[nn] = b2[nn * 16 + c];
    }
    // zero A1 pad region (cols 80..96) once
    if (q == 1) {
        const short8 z8 = {0, 0, 0, 0, 0, 0, 0, 0};
        *(short8*)&A1[wid][c * S1 + 80] = z8;
        *(short8*)&A1[wid][c * S1 + 88] = z8;
    }
    __syncthreads();

    const int bkt = blockIdx.x * 4 + wid;   // one bucket per wave
    if (bkt >= NBUCK) return;

    int cnt = bcur[bkt * 16];
    if (cnt > BCAP) cnt = BCAP;
    const int nt = (cnt + 15) >> 4;
    if (nt == 0) return;

    // ---- LDS counting sort by dst&15 ----
    if (lane < 16) { cnt16[wid][lane] = 0; ctr16[wid][lane] = 0; }
    LDS_FENCE();
    uint2 rec[6];
    const uint2* bp = sde + (size_t)bkt * BCAP;
    #pragma unroll
    for (int j = 0; j < 6; ++j) {
        const int idx = lane + j * 64;
        if (idx < cnt) rec[j] = bp[idx];
    }
    #pragma unroll
    for (int j = 0; j < 6; ++j) {
        const int idx = lane + j * 64;
        if (idx < cnt) atomicAdd(&cnt16[wid][rec[j].y & 15], 1);
    }
    LDS_FENCE();
    if (lane < 16) {
        int s = 0;
        for (int j = 0; j < lane; ++j) s += cnt16[wid][j];
        base16[wid][lane] = s;
    }
    LDS_FENCE();
    #pragma unroll
    for (int j = 0; j < 6; ++j) {
        const int idx = lane + j * 64;
        if (idx < cnt) {
            const int lw = rec[j].y & 15;
            const int pos = base16[wid][lw] + atomicAdd(&ctr16[wid][lw], 1);
            srt[wid][pos] = rec[j];
        }
    }
    for (int idx = cnt + lane; idx < nt * 16; idx += 64) {
        uint2 sv; sv.x = 0u; sv.y = 16u;  // sentinel: low5=16, src=0, e=0
        srt[wid][idx] = sv;
    }
    LDS_FENCE();

    const floatx4 zero = {0.f, 0.f, 0.f, 0.f};

    // ---- prologue: decode tile 0, issue gathers ----
    int dcur; short8 xa, xb; float4 ev;
    {
        const uint2 r0 = srt[wid][c];
        const int low5 = (int)(r0.y & 31u);
        const int sA = (int)(r0.y >> 16);
        dcur = (low5 >= 16) ? NNODES : bkt * 16 + low5;
        const u32 eA = srt[wid][r4].x;
        const u16* xp = xbf + (size_t)sA * 64 + q * 16;
        xa = *(const short8*)xp;
        xb = *(const short8*)(xp + 8);
        ev = *(const float4*)(ef + (size_t)eA * 16 + p4 * 4);
    }

    for (int tt = 0; tt < nt; ++tt) {
        // stage current tile
        u16* arow = &A1[wid][c * S1 + q * 16];
        *(short8*)arow       = xa;
        *(short8*)(arow + 8) = xb;
        {
            short4v e4;
            e4[0] = (short)f2bf(ev.x); e4[1] = (short)f2bf(ev.y);
            e4[2] = (short)f2bf(ev.z); e4[3] = (short)f2bf(ev.w);
            *(short4v*)&A1[wid][r4 * S1 + 64 + p4 * 4] = e4;
        }
        if (q == 0) Ds[wid][c] = dcur;
        LDS_FENCE();

        short8 a1k[3];
        #pragma unroll
        for (int kk = 0; kk < 3; ++kk)
            a1k[kk] = *(const short8*)&A1[wid][c * S1 + kk * 32 + q * 8];

        // prefetch tile tt+1 (indices from LDS, data from global)
        int dnext = dcur;
        if (tt + 1 < nt) {
            const uint2 rn = srt[wid][(tt + 1) * 16 + c];
            const int low5 = (int)(rn.y & 31u);
            const int sN = (int)(rn.y >> 16);
            dnext = (low5 >= 16) ? NNODES : bkt * 16 + low5;
            const u32 eN = srt[wid][(tt + 1) * 16 + r4].x;
            const u16* xp = xbf + (size_t)sN * 64 + q * 16;
            xa = *(const short8*)xp;
            xb = *(const short8*)(xp + 8);
            ev = *(const float4*)(ef + (size_t)eN * 16 + p4 * 4);
        }

        // GEMM1 + bias + relu -> Hs
        #pragma unroll
        for (int nn = 0; nn < 4; ++nn) {
            floatx4 acc = MFMA16(a1k[0], w1f[0][nn], zero);
            acc = MFMA16(a1k[1], w1f[1][nn], acc);
            acc = MFMA16(a1k[2], w1f[2][nn], acc);
            #pragma unroll
            for (int r = 0; r < 4; ++r) {
                const float h = fmaxf(acc[r] + b1v[nn], 0.f);
                Hs[wid][(q * 4 + r) * S2 + nn * 16 + c] = f2bf(h);
            }
        }
        LDS_FENCE();

        short8 a2k[2];
        #pragma unroll
        for (int kk = 0; kk < 2; ++kk)
            a2k[kk] = *(const short8*)&Hs[wid][c * S2 + kk * 32 + q * 8];

        // GEMM2 -> msg (bf16) overlaid into Hs
        #pragma unroll
        for (int nn = 0; nn < 4; ++nn) {
            const short8 wf0 = *(const short8*)&W2f[0][nn][lane * 8];
            const short8 wf1 = *(const short8*)&W2f[1][nn][lane * 8];
            floatx4 mg = MFMA16(a2k[0], wf0, zero);
            mg = MFMA16(a2k[1], wf1, mg);
            #pragma unroll
            for (int r = 0; r < 4; ++r)
                Hs[wid][(q * 4 + r) * S2 + nn * 16 + c] = f2bf(mg[r] + b2v[nn]);
        }
        LDS_FENCE();

        // segmented reduction over sorted dst (lane = column)
        int dc = Ds[wid][0];
        float acc = bf2f(Hs[wid][lane]);
        #pragma unroll
        for (int row = 1; row < 16; ++row) {
            const int d = Ds[wid][row];
            const float v = bf2f(Hs[wid][row * S2 + lane]);
            if (d == dc) {
                acc += v;
            } else {
                atomicAdd(&agg[(size_t)dc * 64 + lane], acc);
                dc = d;
                acc = v;
            }
        }
        atomicAdd(&agg[(size_t)dc * 64 + lane], acc);

        dcur = dnext;
    }
}

// ---------------------------------------------------------------------------
// Node kernel (r7): cat = [xbf | bf16(agg/cnt)]; relu(cat@W3+b3)+x; LayerNorm
// ---------------------------------------------------------------------------
__global__ __launch_bounds__(256) void node_kernel(
    const u16* __restrict__ xbf, const float* __restrict__ w3,
    const float* __restrict__ b3, const float* __restrict__ g,
    const float* __restrict__ bb, const float* __restrict__ agg,
    const int* __restrict__ hist, float* __restrict__ out)
{
    constexpr int S3 = 136;  // 128 + 8 pad
    __shared__ u16 Cs[4][16 * S3];

    const int wid  = threadIdx.x >> 6;
    const int lane = threadIdx.x & 63;
    const int q    = lane >> 4;
    const int c    = lane & 15;

    short8 w3f[4][4];
    #pragma unroll
    for (int kk = 0; kk < 4; ++kk)
        #pragma unroll
        for (int nn = 0; nn < 4; ++nn)
            #pragma unroll
            for (int j = 0; j < 8; ++j) {
                const int k = kk * 32 + q * 8 + j;
                w3f[kk][nn][j] = (short)f2bf(w3[k * 64 + nn * 16 + c]);
            }
    float b3v[4], gv[4], bv[4];
    #pragma unroll
    for (int nn = 0; nn < 4; ++nn) {
        b3v[nn] = b3[nn * 16 + c];
        gv[nn]  = g[nn * 16 + c];
        bv[nn]  = bb[nn * 16 + c];
    }

    const floatx4 zero = {0.f, 0.f, 0.f, 0.f};
    const int ntile = NNODES / 16;  // 3125

    for (int t = blockIdx.x * 4 + wid; t < ntile; t += gridDim.x * 4) {
        const int n0 = t * 16;
        const int node = n0 + c;
        u16* crow = &Cs[wid][c * S3];

        if (q < 2) {
            const u16* xp = xbf + (size_t)node * 64 + q * 32;
            *(short8*)&crow[q * 32]      = *(const short8*)xp;
            *(short8*)&crow[q * 32 + 8]  = *(const short8*)(xp + 8);
            *(short8*)&crow[q * 32 + 16] = *(const short8*)(xp + 16);
            *(short8*)&crow[q * 32 + 24] = *(const short8*)(xp + 24);
        } else {
            const int p = q - 2;
            const float inv = 1.0f / ((float)hist[node] + 1e-8f);
            const float* ap = agg + (size_t)node * 64 + p * 32;
            #pragma unroll
            for (int gi = 0; gi < 4; ++gi) {
                const float4 v0 = *(const float4*)(ap + gi * 8);
                const float4 v1 = *(const float4*)(ap + gi * 8 + 4);
                short8 o;
                o[0] = (short)f2bf(v0.x * inv);
                o[1] = (short)f2bf(v0.y * inv);
                o[2] = (short)f2bf(v0.z * inv);
                o[3] = (short)f2bf(v0.w * inv);
                o[4] = (short)f2bf(v1.x * inv);
                o[5] = (short)f2bf(v1.y * inv);
                o[6] = (short)f2bf(v1.z * inv);
                o[7] = (short)f2bf(v1.w * inv);
                *(short8*)&crow[64 + p * 32 + gi * 8] = o;
            }
        }
        LDS_FENCE();

        short8 af[4];
        #pragma unroll
        for (int kk = 0; kk < 4; ++kk)
            af[kk] = *(const short8*)&Cs[wid][c * S3 + kk * 32 + q * 8];

        float y[4][4];
        float s[4]  = {0.f, 0.f, 0.f, 0.f};
        float ss[4] = {0.f, 0.f, 0.f, 0.f};
        #pragma unroll
        for (int nn = 0; nn < 4; ++nn) {
            floatx4 acc = MFMA16(af[0], w3f[0][nn], zero);
            acc = MFMA16(af[1], w3f[1][nn], acc);
            acc = MFMA16(af[2], w3f[2][nn], acc);
            acc = MFMA16(af[3], w3f[3][nn], acc);
            #pragma unroll
            for (int r = 0; r < 4; ++r) {
                const float upd = fmaxf(acc[r] + b3v[nn], 0.f);
                const float xv = bf2f(Cs[wid][(q * 4 + r) * S3 + nn * 16 + c]);
                const float yy = upd + xv;
                y[r][nn] = yy;
                s[r] += yy;
                ss[r] += yy * yy;
            }
        }

        #pragma unroll
        for (int r = 0; r < 4; ++r) {
            float sr = s[r], sq = ss[r];
            #pragma unroll
            for (int off = 1; off < 16; off <<= 1) {
                sr += __shfl_xor(sr, off);
                sq += __shfl_xor(sq, off);
            }
            const float mu  = sr * (1.0f / 64.0f);
            const float var = sq * (1.0f / 64.0f) - mu * mu;
            const float rs  = rsqrtf(var + 1e-5f);
            float* op = out + (size_t)(n0 + q * 4 + r) * 64 + c;
            #pragma unroll
            for (int nn = 0; nn < 4; ++nn)
                op[nn * 16] = (y[r][nn] - mu) * rs * gv[nn] + bv[nn];
        }
    }
}

extern "C" void kernel_launch(void* const* d_in, const int* in_sizes, int n_in,
                              void* d_out, int out_size, void* d_ws, size_t ws_size,
                              hipStream_t stream) {
    const float* x   = (const float*)d_in[0];
    const int*   ei  = (const int*)d_in[1];
    const float* ef  = (const float*)d_in[2];
    const float* w1  = (const float*)d_in[3];
    const float* b1  = (const float*)d_in[4];
    const float* w2  = (const float*)d_in[5];
    const float* b2  = (const float*)d_in[6];
    const float* w3  = (const float*)d_in[7];
    const float* b3  = (const float*)d_in[8];
    const float* g   = (const float*)d_in[9];
    const float* bb  = (const float*)d_in[10];
    int* ws = (int*)d_ws;

    // ws layout (u32 units):
    //   agg   : 0         (50001 x 64 = 3,200,064 floats; last row = sentinel)
    //   hist  : 3,200,064 (50,000)
    //   bcur  : 3,250,064 (3125 x 16, stride-16 padded)
    //   xbf   : 3,300,064 (u16 x 3.2M = 1,600,000 u32)
    //   sde   : 4,900,064 (3125 x 368 uint2 = 2,300,000 u32)  total 28.8 MB
    float* agg  = (float*)d_ws;
    int*   hist = ws + 3200064;
    int*   bcur = ws + 3250064;
    u16*   xbf  = (u16*)(ws + 3300064);
    uint2* sde  = (uint2*)(ws + 4900064);

    prep_kernel<<<1024, 256, 0, stream>>>(x, ws);
    scatter_kernel<<<(NE + 255) / 256, 256, 0, stream>>>(ei, hist, bcur, sde);
    edge_kernel<<<(NBUCK + 3) / 4, 256, 0, stream>>>(xbf, ef, w1, b1, w2, b2,
                                                     sde, bcur, agg);
    node_kernel<<<782, 256, 0, stream>>>(xbf, w3, b3, g, bb, agg, hist,
                                         (float*)d_out);
}